// Round 1
// baseline (2067.325 us; speedup 1.0000x reference)
//
#include <hip/hip_runtime.h>
#include <cstdint>
#include <cstddef>

#define D_ 1024
#define M_ 131072
#define R_ 1024   /* B*S rows */

typedef float  f32x4 __attribute__((ext_vector_type(4)));
typedef __bf16 bfrag __attribute__((ext_vector_type(8)));
typedef __bf16 bf4   __attribute__((ext_vector_type(4)));

__device__ __forceinline__ void gload16(const void* g, void* l) {
  __builtin_amdgcn_global_load_lds(
      (const __attribute__((address_space(1))) unsigned int*)g,
      (__attribute__((address_space(3))) unsigned int*)l, 16, 0, 0);
}

// ---------------- BT GEMM: C[row, col] = sum_k A[row,k]*B[col,k] ----------------
// ADT/BDT: 0 = bf16 (global_load_lds staging), 1 = f32 (reg-stage + cvt)
// EPI: 0 bf16 C; 1 bf16 (acc+colvec[col])*scale; 2 f32 C (+split-K via blockIdx.z);
//      3 bf16 acc+colvec[col]; 4 f32 acc+colvec[col]+xres[row*1024+col]
template<int ADT, int BDT, int EPI>
__global__ __launch_bounds__(256)
void gemm_bt(const void* __restrict__ Ap, const void* __restrict__ Bp,
             void* __restrict__ Cp, int K, size_t lda, size_t ldb, size_t ldc,
             size_t kofs, const float* __restrict__ colvec,
             const float* __restrict__ xres, float scale) {
  __shared__ char Al[16384];
  __shared__ char Bl[16384];
  const int row0 = blockIdx.x * 128;
  const int col0 = blockIdx.y * 128;
  const int tid = threadIdx.x;
  const int lane = tid & 63;
  const int w = tid >> 6;
  const int wr = w >> 1, wc = w & 1;
  const size_t kbase = kofs * (size_t)blockIdx.z;

  f32x4 acc[4][4];
#pragma unroll
  for (int m = 0; m < 4; ++m)
#pragma unroll
    for (int n = 0; n < 4; ++n) acc[m][n] = (f32x4)0.0f;

  const int nk = K >> 6;
  for (int kt = 0; kt < nk; ++kt) {
    const size_t k0 = kbase + (size_t)kt * 64;
    // ---- stage A tile [128 x 64] ----
    if constexpr (ADT == 0) {
      const __bf16* A = (const __bf16*)Ap;
#pragma unroll
      for (int c = 0; c < 4; ++c) {
        int s = c * 4096 + w * 1024 + lane * 16;
        int r = s >> 7;
        int g = (s >> 4) & 7;
        int sb = (g * 16) ^ ((r & 7) << 4);
        gload16(A + (size_t)(row0 + r) * lda + k0 + (sb >> 1), Al + c * 4096 + w * 1024);
      }
    } else {
      const float* A = (const float*)Ap;
      int kg = tid & 15;
#pragma unroll
      for (int p = 0; p < 8; ++p) {
        int r = (tid >> 4) + p * 16;
        f32x4 v = *(const f32x4*)(A + (size_t)(row0 + r) * lda + k0 + kg * 4);
        bf4 o; o[0] = (__bf16)v[0]; o[1] = (__bf16)v[1]; o[2] = (__bf16)v[2]; o[3] = (__bf16)v[3];
        *(bf4*)(Al + r * 128 + ((kg * 8) ^ ((r & 7) << 4))) = o;
      }
    }
    // ---- stage B tile [128 x 64] ----
    if constexpr (BDT == 0) {
      const __bf16* B = (const __bf16*)Bp;
#pragma unroll
      for (int c = 0; c < 4; ++c) {
        int s = c * 4096 + w * 1024 + lane * 16;
        int r = s >> 7;
        int g = (s >> 4) & 7;
        int sb = (g * 16) ^ ((r & 7) << 4);
        gload16(B + (size_t)(col0 + r) * ldb + k0 + (sb >> 1), Bl + c * 4096 + w * 1024);
      }
    } else {
      const float* B = (const float*)Bp;
      int kg = tid & 15;
#pragma unroll
      for (int p = 0; p < 8; ++p) {
        int r = (tid >> 4) + p * 16;
        f32x4 v = *(const f32x4*)(B + (size_t)(col0 + r) * ldb + k0 + kg * 4);
        bf4 o; o[0] = (__bf16)v[0]; o[1] = (__bf16)v[1]; o[2] = (__bf16)v[2]; o[3] = (__bf16)v[3];
        *(bf4*)(Bl + r * 128 + ((kg * 8) ^ ((r & 7) << 4))) = o;
      }
    }
    __syncthreads();
    bfrag af[4][2], bfr[4][2];
#pragma unroll
    for (int m = 0; m < 4; ++m)
#pragma unroll
      for (int x = 0; x < 2; ++x) {
        int r = wr * 64 + m * 16 + (lane & 15);
        int g = x * 4 + (lane >> 4);
        af[m][x] = *(const bfrag*)(Al + r * 128 + ((g * 16) ^ ((r & 7) << 4)));
      }
#pragma unroll
    for (int n = 0; n < 4; ++n)
#pragma unroll
      for (int x = 0; x < 2; ++x) {
        int r = wc * 64 + n * 16 + (lane & 15);
        int g = x * 4 + (lane >> 4);
        bfr[n][x] = *(const bfrag*)(Bl + r * 128 + ((g * 16) ^ ((r & 7) << 4)));
      }
#pragma unroll
    for (int x = 0; x < 2; ++x)
#pragma unroll
      for (int m = 0; m < 4; ++m)
#pragma unroll
        for (int n = 0; n < 4; ++n)
          acc[m][n] = __builtin_amdgcn_mfma_f32_16x16x32_bf16(af[m][x], bfr[n][x], acc[m][n], 0, 0, 0);
    __syncthreads();
  }

  // ---- epilogue ----
  const int cc = lane & 15;
  const int rr4 = (lane >> 4) * 4;
  float* Cf = (float*)Cp;
  if constexpr (EPI == 2) Cf += (size_t)blockIdx.z * 1048576;  // split-K partials
#pragma unroll
  for (int m = 0; m < 4; ++m)
#pragma unroll
    for (int n = 0; n < 4; ++n) {
      int grow0 = row0 + wr * 64 + m * 16 + rr4;
      int gcol = col0 + wc * 64 + n * 16 + cc;
#pragma unroll
      for (int j = 0; j < 4; ++j) {
        int grow = grow0 + j;
        float v = acc[m][n][j];
        if constexpr (EPI == 0) ((__bf16*)Cp)[(size_t)grow * ldc + gcol] = (__bf16)v;
        else if constexpr (EPI == 1) ((__bf16*)Cp)[(size_t)grow * ldc + gcol] = (__bf16)((v + colvec[gcol]) * scale);
        else if constexpr (EPI == 2) Cf[(size_t)grow * ldc + gcol] = v;
        else if constexpr (EPI == 3) ((__bf16*)Cp)[(size_t)grow * ldc + gcol] = (__bf16)(v + colvec[gcol]);
        else Cf[(size_t)grow * ldc + gcol] = v + colvec[gcol] + xres[(size_t)grow * 1024 + gcol];
      }
    }
}

// ---------------- transpose + cvt: dstT[c,r] = src[r,c] (bf16); optional dst[r,c] copy ----------------
__global__ __launch_bounds__(256)
void k_tr(const float* __restrict__ src, __bf16* __restrict__ dstT,
          __bf16* __restrict__ dst, int R, int C) {
  __shared__ float tile[64][65];
  int r0 = blockIdx.x * 64, c0 = blockIdx.y * 64;
  int t = threadIdx.x, cg = t & 15, rr = t >> 4;
#pragma unroll
  for (int s = 0; s < 4; ++s) {
    int row = rr + s * 16;
    f32x4 v = *(const f32x4*)(src + (size_t)(r0 + row) * C + c0 + cg * 4);
    tile[row][cg * 4 + 0] = v[0]; tile[row][cg * 4 + 1] = v[1];
    tile[row][cg * 4 + 2] = v[2]; tile[row][cg * 4 + 3] = v[3];
    if (dst) {
      bf4 o; o[0] = (__bf16)v[0]; o[1] = (__bf16)v[1]; o[2] = (__bf16)v[2]; o[3] = (__bf16)v[3];
      *(bf4*)(dst + (size_t)(r0 + row) * C + c0 + cg * 4) = o;
    }
  }
  __syncthreads();
#pragma unroll
  for (int s = 0; s < 4; ++s) {
    int dd = rr + s * 16;
    bf4 o;
    o[0] = (__bf16)tile[cg * 4 + 0][dd]; o[1] = (__bf16)tile[cg * 4 + 1][dd];
    o[2] = (__bf16)tile[cg * 4 + 2][dd]; o[3] = (__bf16)tile[cg * 4 + 3][dd];
    *(bf4*)(dstT + (size_t)(c0 + dd) * R + r0 + cg * 4) = o;
  }
}

// qb[in] = sum_o bq[o]*Wk[in,o]
__global__ __launch_bounds__(256)
void k_qb(const float* __restrict__ bq, const float* __restrict__ Wk, float* __restrict__ qb) {
  int in = blockIdx.x, t = threadIdx.x;
  float s = 0.f;
  for (int o = t; o < 1024; o += 256) s += bq[o] * Wk[(size_t)in * 1024 + o];
  for (int o = 32; o > 0; o >>= 1) s += __shfl_xor(s, o);
  __shared__ float red[4];
  if ((t & 63) == 0) red[t >> 6] = s;
  __syncthreads();
  if (t == 0) qb[in] = red[0] + red[1] + red[2] + red[3];
}

// per-(row, chunk) max & sumexp over 16384 bf16 scores
__global__ __launch_bounds__(256)
void k_stats(const __bf16* __restrict__ s, float2* __restrict__ part) {
  const int row = blockIdx.y, ch = blockIdx.x, t = threadIdx.x;
  const __bf16* base = s + (size_t)row * M_ + (size_t)ch * 16384 + (size_t)t * 8;
  bfrag v[8];
#pragma unroll
  for (int i = 0; i < 8; ++i) v[i] = *(const bfrag*)(base + i * 2048);
  float lm = -1e30f;
#pragma unroll
  for (int i = 0; i < 8; ++i)
#pragma unroll
    for (int j = 0; j < 8; ++j) lm = fmaxf(lm, (float)v[i][j]);
  __shared__ float red[4];
  for (int o = 32; o > 0; o >>= 1) lm = fmaxf(lm, __shfl_xor(lm, o));
  if ((t & 63) == 0) red[t >> 6] = lm;
  __syncthreads();
  float bmax = fmaxf(fmaxf(red[0], red[1]), fmaxf(red[2], red[3]));
  float ls = 0.f;
#pragma unroll
  for (int i = 0; i < 8; ++i)
#pragma unroll
    for (int j = 0; j < 8; ++j) ls += __expf((float)v[i][j] - bmax);
  for (int o = 32; o > 0; o >>= 1) ls += __shfl_xor(ls, o);
  __syncthreads();
  if ((t & 63) == 0) red[t >> 6] = ls;
  __syncthreads();
  if (t == 0) part[(size_t)row * 8 + ch] = make_float2(bmax, red[0] + red[1] + red[2] + red[3]);
}

__global__ __launch_bounds__(256)
void k_merge(const float2* __restrict__ part, float* __restrict__ rowM, float* __restrict__ rowIL) {
  int i = blockIdx.x * 256 + threadIdx.x;
  float M = -1e30f;
#pragma unroll
  for (int c = 0; c < 8; ++c) M = fmaxf(M, part[(size_t)i * 8 + c].x);
  float L = 0.f;
#pragma unroll
  for (int c = 0; c < 8; ++c) L += part[(size_t)i * 8 + c].y * __expf(part[(size_t)i * 8 + c].x - M);
  rowM[i] = M;
  rowIL[i] = 1.0f / L;
}

// in-place p = exp(s - rowM)
__global__ __launch_bounds__(256)
void k_exp(__bf16* __restrict__ s, const float* __restrict__ rowM) {
  size_t b = blockIdx.x;
  int t = threadIdx.x;
  float M = rowM[(int)(b >> 6)];
  __bf16* p = s + b * 2048 + (size_t)t * 8;
  bfrag v = *(const bfrag*)p;
#pragma unroll
  for (int j = 0; j < 8; ++j) v[j] = (__bf16)__expf((float)v[j] - M);
  *(bfrag*)p = v;
}

// r[i,d] = (sum_z part[z,i,d]) * rowIL[i]  -> bf16
__global__ __launch_bounds__(256)
void k_rpv(const float* __restrict__ part, const float* __restrict__ rowIL, __bf16* __restrict__ r) {
  int idx = blockIdx.x * 256 + threadIdx.x;
  float a = 0.f;
#pragma unroll
  for (int z = 0; z < 8; ++z) a += part[(size_t)z * 1048576 + idx];
  r[idx] = (__bf16)(a * rowIL[idx >> 10]);
}

// row LayerNorm
__global__ __launch_bounds__(256)
void k_ln(const float* __restrict__ pre, const float* __restrict__ gam,
          const float* __restrict__ bet, float* __restrict__ out) {
  int row = blockIdx.x, t = threadIdx.x;
  f32x4 v = *(const f32x4*)(pre + (size_t)row * 1024 + t * 4);
  float s = v[0] + v[1] + v[2] + v[3];
  float q = v[0] * v[0] + v[1] * v[1] + v[2] * v[2] + v[3] * v[3];
  for (int o = 32; o > 0; o >>= 1) { s += __shfl_xor(s, o); q += __shfl_xor(q, o); }
  __shared__ float rs_[4], rq_[4];
  if ((t & 63) == 0) { rs_[t >> 6] = s; rq_[t >> 6] = q; }
  __syncthreads();
  s = rs_[0] + rs_[1] + rs_[2] + rs_[3];
  q = rq_[0] + rq_[1] + rq_[2] + rq_[3];
  float mu = s * (1.0f / 1024.0f);
  float var = q * (1.0f / 1024.0f) - mu * mu;
  float rstd = rsqrtf(var + 1e-5f);
  float* op = out + (size_t)row * 1024 + t * 4;
#pragma unroll
  for (int j = 0; j < 4; ++j) op[j] = (v[j] - mu) * rstd * gam[t * 4 + j] + bet[t * 4 + j];
}

extern "C" void kernel_launch(void* const* d_in, const int* in_sizes, int n_in,
                              void* d_out, int out_size, void* d_ws, size_t ws_size,
                              hipStream_t stream) {
  const float* x    = (const float*)d_in[0];
  const float* bank = (const float*)d_in[1];
  const float* Wq   = (const float*)d_in[2];
  const float* bq   = (const float*)d_in[3];
  const float* Wk   = (const float*)d_in[4];
  /* d_in[5] = bk: row-constant in scores -> softmax-invariant -> unused */
  const float* Wv   = (const float*)d_in[6];
  const float* bv   = (const float*)d_in[7];
  const float* Wo   = (const float*)d_in[8];
  const float* bo   = (const float*)d_in[9];
  const float* gam  = (const float*)d_in[10];
  const float* bet  = (const float*)d_in[11];

  char* w = (char*)d_ws;
  __bf16* bankT  = (__bf16*)(w);                               // 256 MB: bank^T bf16 [D, M]
  __bf16* scores = (__bf16*)(w + (size_t)268435456);           // 256 MB: scores/p bf16 [R, M]
  float*  part   = (float*)(w + (size_t)536870912);            // 32 MB: PV split-K partials
  char* sm = w + (size_t)536870912 + (size_t)33554432;
  __bf16* WqkT = (__bf16*)(sm);                  // [in, k] = Wk·Wq^T
  __bf16* q2s  = (__bf16*)(sm + (2u << 20));     // scaled folded queries
  __bf16* WvT  = (__bf16*)(sm + (4u << 20));
  __bf16* WoT  = (__bf16*)(sm + (6u << 20));
  __bf16* rbuf = (__bf16*)(sm + (8u << 20));     // attn@bank (bf16)
  __bf16* retr = (__bf16*)(sm + (10u << 20));    // retrieved (bf16)
  float*  pre  = (float*)(sm + (12u << 20));     // pre-LN f32
  float*  qb   = (float*)(sm + (16u << 20));
  float2* stp  = (float2*)(sm + (17u << 20));
  float*  rowM = (float*)(sm + (18u << 20));
  float*  rowIL= (float*)(sm + (19u << 20));

  dim3 b256(256);

  // bank -> bankT (bf16 [D, M]); weight transposes
  k_tr<<<dim3(2048, 16), b256, 0, stream>>>(bank, bankT, nullptr, M_, D_);
  k_tr<<<dim3(16, 16), b256, 0, stream>>>(Wv, WvT, nullptr, D_, D_);
  k_tr<<<dim3(16, 16), b256, 0, stream>>>(Wo, WoT, nullptr, D_, D_);
  k_qb<<<dim3(1024), b256, 0, stream>>>(bq, Wk, qb);

  // WqkT[in,k] = sum_o Wk[in,o]*Wq[k,o]
  gemm_bt<1, 1, 0><<<dim3(8, 8), b256, 0, stream>>>(Wk, Wq, WqkT, 1024, 1024, 1024, 1024, 0, nullptr, nullptr, 0.f);
  // q2s[i,in] = ((sum_k x[i,k]*WqkT[in,k]) + qb[in]) * scale
  gemm_bt<1, 0, 1><<<dim3(8, 8), b256, 0, stream>>>(x, WqkT, q2s, 1024, 1024, 1024, 1024, 0, qb, nullptr, 0.03125f);
  // scores[i,m] = sum_in q2s[i,in]*bank[m,in]   (B staged from f32 bank)
  gemm_bt<0, 1, 0><<<dim3(8, 1024), b256, 0, stream>>>(q2s, bank, scores, 1024, 1024, 1024, 131072, 0, nullptr, nullptr, 0.f);
  // softmax stats
  k_stats<<<dim3(8, 1024), b256, 0, stream>>>(scores, stp);
  k_merge<<<dim3(4), b256, 0, stream>>>(stp, rowM, rowIL);
  k_exp<<<dim3(65536), b256, 0, stream>>>(scores, rowM);
  // PV split-K: part[z,i,d] = sum_{m in chunk z} p[i,m]*bankT[d,m]
  gemm_bt<0, 0, 2><<<dim3(8, 8, 8), b256, 0, stream>>>(scores, bankT, part, 16384, 131072, 131072, 1024, 16384, nullptr, nullptr, 0.f);
  k_rpv<<<dim3(4096), b256, 0, stream>>>(part, rowIL, rbuf);
  // retrieved = r@Wv + bv
  gemm_bt<0, 0, 3><<<dim3(8, 8), b256, 0, stream>>>(rbuf, WvT, retr, 1024, 1024, 1024, 1024, 0, bv, nullptr, 0.f);
  // pre = retrieved@Wo + bo + x
  gemm_bt<0, 0, 4><<<dim3(8, 8), b256, 0, stream>>>(retr, WoT, pre, 1024, 1024, 1024, 1024, 0, bo, x, 0.f);
  // LayerNorm -> out
  k_ln<<<dim3(1024), b256, 0, stream>>>(pre, gam, bet, (float*)d_out);
}